// Round 2
// baseline (1976.785 us; speedup 1.0000x reference)
//
#include <hip/hip_runtime.h>
#include <float.h>
#include <limits.h>
#include <math.h>

// Problem constants
#define B_      16
#define C_      256
#define HW      1024            // 32*32
#define ROWS    (B_*HW)         // 16384
#define NCODE   8192
#define KDIM    256

// GEMM tiling
#define BM 64
#define BN 64
#define BK 16
#define NTILES (NCODE/BN)       // 128

struct Top2 { float v1, v2; int i1, i2; };
struct Top4 { float v[4]; int i[4]; };

// ---------------------------------------------------------------------------
// c_sq[j] = fl32( exact sum_k w[j,k]^2 )  (f64 accumulate -> f32)
__global__ __launch_bounds__(256)
void csq_kernel(const float* __restrict__ w, float* __restrict__ csq) {
    int gw   = (blockIdx.x * 256 + threadIdx.x) >> 6;   // code row
    int lane = threadIdx.x & 63;
    if (gw >= NCODE) return;
    float4 v = *(const float4*)(w + (size_t)gw * KDIM + lane * 4);
    double s = (double)v.x*v.x + (double)v.y*v.y + (double)v.z*v.z + (double)v.w*v.w;
    #pragma unroll
    for (int off = 1; off < 64; off <<= 1) s += __shfl_xor(s, off, 64);
    if (lane == 0) csq[gw] = (float)s;
}

// ---------------------------------------------------------------------------
// Stage 1: f32 tiled screening GEMM + fused per-row running top-2 per thread,
// merged to per-row top-4 candidates. Screening only: needs ~1e-5 accuracy.
__global__ __launch_bounds__(256)
void stage1_kernel(const float* __restrict__ x, const float* __restrict__ w,
                   const float* __restrict__ csq, Top4* __restrict__ top4out)
{
    __shared__ float As[BK][BM];       // [k][row]
    __shared__ float Bs[BK][BN];       // [k][code]
    __shared__ Top2  red[BM][16];      // cross-thread reduce

    const int tid = threadIdx.x;
    const int tx  = tid & 15;          // code group
    const int ty  = tid >> 4;          // row group
    const int r0  = blockIdx.x * BM;
    const int b   = r0 >> 10;
    const int p0  = r0 & 1023;
    const float* xb = x + (size_t)b * (C_*HW) + p0;   // x[b,k,p0+p] = xb[k*HW+p]

    float v1[4], v2[4]; int i1[4], i2[4];
    #pragma unroll
    for (int i = 0; i < 4; ++i) { v1[i]=FLT_MAX; v2[i]=FLT_MAX; i1[i]=INT_MAX; i2[i]=INT_MAX; }

    const int pA  = tid & 63;
    const int kA  = tid >> 6;
    const int jB  = tid >> 2;
    const int ksB = tid & 3;

    for (int jt = 0; jt < NTILES; ++jt) {
        const int j0 = jt * BN;
        float acc[4][4];
        #pragma unroll
        for (int i = 0; i < 4; ++i)
            #pragma unroll
            for (int j = 0; j < 4; ++j) acc[i][j] = 0.f;

        for (int kt = 0; kt < KDIM/BK; ++kt) {
            const int k0 = kt * BK;
            #pragma unroll
            for (int it = 0; it < 4; ++it) {
                int krel = kA + (it << 2);
                As[krel][pA] = xb[(size_t)(k0 + krel) * HW + pA];
            }
            {
                float4 v = *(const float4*)(w + (size_t)(j0 + jB) * KDIM + k0 + ksB*4);
                Bs[ksB*4+0][jB] = v.x; Bs[ksB*4+1][jB] = v.y;
                Bs[ksB*4+2][jB] = v.z; Bs[ksB*4+3][jB] = v.w;
            }
            __syncthreads();
            #pragma unroll
            for (int kk = 0; kk < BK; ++kk) {
                float4 a  = *(const float4*)&As[kk][ty*4];
                float4 b4 = *(const float4*)&Bs[kk][tx*4];
                float av[4] = {a.x, a.y, a.z, a.w};
                float bv[4] = {b4.x, b4.y, b4.z, b4.w};
                #pragma unroll
                for (int i = 0; i < 4; ++i)
                    #pragma unroll
                    for (int j = 0; j < 4; ++j)
                        acc[i][j] = fmaf(av[i], bv[j], acc[i][j]);
            }
            __syncthreads();
        }

        float4 cs = *(const float4*)(csq + j0 + tx*4);
        float csv[4] = {cs.x, cs.y, cs.z, cs.w};
        #pragma unroll
        for (int j = 0; j < 4; ++j) {
            int idx = j0 + tx*4 + j;
            #pragma unroll
            for (int i = 0; i < 4; ++i) {
                float d = csv[j] - 2.0f * acc[i][j];
                if (d < v1[i] || (d == v1[i] && idx < i1[i])) {
                    v2[i]=v1[i]; i2[i]=i1[i]; v1[i]=d; i1[i]=idx;
                } else if (d < v2[i] || (d == v2[i] && idx < i2[i])) {
                    v2[i]=d; i2[i]=idx;
                }
            }
        }
    }

    #pragma unroll
    for (int i = 0; i < 4; ++i) {
        Top2 t; t.v1 = v1[i]; t.v2 = v2[i]; t.i1 = i1[i]; t.i2 = i2[i];
        red[ty*4 + i][tx] = t;
    }
    __syncthreads();

    // merge 16 threads' top-2 -> row top-4 (sorted, tie -> lower index)
    if (tid < BM) {
        float rv[4] = {FLT_MAX, FLT_MAX, FLT_MAX, FLT_MAX};
        int   ri[4] = {INT_MAX, INT_MAX, INT_MAX, INT_MAX};
        for (int t = 0; t < 16; ++t) {
            Top2 e = red[tid][t];
            float ev[2] = { e.v1, e.v2 };
            int   ei[2] = { e.i1, e.i2 };
            for (int q = 0; q < 2; ++q) {
                float v = ev[q]; int i = ei[q];
                if (v < rv[3] || (v == rv[3] && i < ri[3])) {
                    rv[3] = v; ri[3] = i;
                    #pragma unroll
                    for (int k = 3; k > 0; --k) {
                        bool sw = (rv[k] < rv[k-1]) || (rv[k] == rv[k-1] && ri[k] < ri[k-1]);
                        if (!sw) break;
                        float tv = rv[k]; rv[k] = rv[k-1]; rv[k-1] = tv;
                        int   ti = ri[k]; ri[k] = ri[k-1]; ri[k-1] = ti;
                    }
                }
            }
        }
        Top4 o;
        #pragma unroll
        for (int k = 0; k < 4; ++k) { o.v[k] = rv[k]; o.i[k] = ri[k]; }
        top4out[r0 + tid] = o;
    }
}

// ---------------------------------------------------------------------------
// Stage 2: emulate the reference's f32 arithmetic for the 4 candidates.
//   d32[j] = fl32( fl32(S32 + csq32[j]) - fl32(2*dot_exact) )
// argmin with numpy first-min (lowest index) tie semantics on the ROUNDED
// values. S32 = fl32(exact x_sq) -- any consistent rounding works because a
// row-constant shift by a grid multiple commutes with the final rounding.
__global__ __launch_bounds__(256)
void refine_kernel(const float* __restrict__ x, const float* __restrict__ w,
                   const float* __restrict__ csq, const Top4* __restrict__ top4,
                   int* __restrict__ codes, float* __restrict__ code_out)
{
    int row  = blockIdx.x * 4 + (threadIdx.x >> 6);
    int lane = threadIdx.x & 63;
    if (row >= ROWS) return;
    int b = row >> 10, p = row & 1023;
    const float* xb = x + (size_t)b * (C_*HW) + p;

    float xs[4];
    #pragma unroll
    for (int m = 0; m < 4; ++m) xs[m] = xb[(size_t)(lane*4 + m) * HW];

    double ss = (double)xs[0]*xs[0] + (double)xs[1]*xs[1]
              + (double)xs[2]*xs[2] + (double)xs[3]*xs[3];
    #pragma unroll
    for (int off = 1; off < 64; off <<= 1) ss += __shfl_xor(ss, off, 64);
    float S32 = (float)ss;

    Top4 t4 = top4[row];
    float bestd = FLT_MAX; int besti = INT_MAX;
    #pragma unroll
    for (int c = 0; c < 4; ++c) {
        int ci = t4.i[c];
        float4 wv = *(const float4*)(w + (size_t)ci * KDIM + lane*4);
        double acc = (double)wv.x*xs[0] + (double)wv.y*xs[1]
                   + (double)wv.z*xs[2] + (double)wv.w*xs[3];
        #pragma unroll
        for (int off = 1; off < 64; off <<= 1) acc += __shfl_xor(acc, off, 64);
        float tt = (float)(2.0 * acc);     // fl32(2*m_exact)
        float sc = S32 + csq[ci];          // fl32(S + c_sq)
        float d  = sc - tt;                // fl32( ... - ... )
        if (d < bestd || (d == bestd && ci < besti)) { bestd = d; besti = ci; }
    }

    if (lane == 0) {
        codes[row]    = besti;
        code_out[row] = (float)besti;
    }
}

// ---------------------------------------------------------------------------
// Outputs: x_q gather (coalesced over p) + per-block f64 loss partials.
__global__ __launch_bounds__(256)
void output_kernel(const float* __restrict__ x, const float* __restrict__ w,
                   const int* __restrict__ codes, float* __restrict__ xq,
                   double* __restrict__ partials)
{
    int bid = blockIdx.x;               // = b*1024 + c*4 + pc
    int pc  = bid & 3;
    int c   = (bid >> 2) & 255;
    int b   = bid >> 10;
    int p   = pc * 256 + threadIdx.x;
    int r   = b * 1024 + p;
    int code = codes[r];
    size_t o = (size_t)b * (C_*HW) + (size_t)c * HW + p;
    float val  = w[(size_t)code * KDIM + c];
    xq[o] = val;
    float diff = val - x[o];
    double sq = (double)diff * (double)diff;

    __shared__ double sred[256];
    sred[threadIdx.x] = sq;
    __syncthreads();
    for (int s = 128; s > 0; s >>= 1) {
        if (threadIdx.x < s) sred[threadIdx.x] += sred[threadIdx.x + s];
        __syncthreads();
    }
    if (threadIdx.x == 0) partials[bid] = sred[0];
}

// loss = 1.25 * mean((x_q - xt)^2); deterministic fixed-order f64 reduce
__global__ __launch_bounds__(256)
void loss_kernel(const double* __restrict__ partials, float* __restrict__ loss_out)
{
    __shared__ double sred[256];
    double s = 0.0;
    for (int i = threadIdx.x; i < 16384; i += 256) s += partials[i];
    sred[threadIdx.x] = s;
    __syncthreads();
    for (int k = 128; k > 0; k >>= 1) {
        if (threadIdx.x < k) sred[threadIdx.x] += sred[threadIdx.x + k];
        __syncthreads();
    }
    if (threadIdx.x == 0)
        loss_out[0] = (float)(sred[0] * (1.25 / (double)(B_*C_*HW)));
}

// ---------------------------------------------------------------------------
extern "C" void kernel_launch(void* const* d_in, const int* in_sizes, int n_in,
                              void* d_out, int out_size, void* d_ws, size_t ws_size,
                              hipStream_t stream)
{
    const float* x = (const float*)d_in[0];   // (16,256,32,32)
    const float* w = (const float*)d_in[1];   // (8193,256); codebook = first 8192 rows
    float* out    = (float*)d_out;
    float* xq     = out;                       // 4194304 elems
    float* loss   = out + 4194304;             // 1 elem
    float* code_f = out + 4194305;             // 16384 elems

    char* ws = (char*)d_ws;
    float*  csq      = (float*)(ws);                    //  32 KB
    Top4*   top4     = (Top4*) (ws + 32*1024);          // 512 KB
    int*    codes    = (int*)  (ws + 544*1024);         //  64 KB
    double* partials = (double*)(ws + 608*1024);        // 128 KB

    csq_kernel   <<<NCODE/4,  256, 0, stream>>>(w, csq);
    stage1_kernel<<<ROWS/BM,  256, 0, stream>>>(x, w, csq, top4);
    refine_kernel<<<ROWS/4,   256, 0, stream>>>(x, w, csq, top4, codes, code_f);
    output_kernel<<<16384,    256, 0, stream>>>(x, w, codes, xq, partials);
    loss_kernel  <<<1,        256, 0, stream>>>(partials, loss);
}

// Round 4
// 206.160 us; speedup vs baseline: 9.5886x; 9.5886x over previous
//
#include <hip/hip_runtime.h>
#include <float.h>
#include <limits.h>
#include <math.h>

// Problem constants
#define B_      16
#define C_      256
#define HW      1024
#define ROWS    (B_*HW)         // 16384
#define NCODE   8192
#define KDIM    256

typedef __attribute__((ext_vector_type(4))) float f32x4;
typedef __attribute__((ext_vector_type(8))) short bf16x8;

__device__ __forceinline__ unsigned short f2bf(float f) {
    unsigned u = __builtin_bit_cast(unsigned, f);
    unsigned r = (u + 0x7FFFu + ((u >> 16) & 1u)) >> 16;
    return (unsigned short)r;
}
__device__ __forceinline__ unsigned mono(float d) {
    unsigned u = __builtin_bit_cast(unsigned, d);
    return u ^ ((unsigned)((int)u >> 31) | 0x80000000u);
}
__device__ __forceinline__ unsigned umn(unsigned a, unsigned b){ return a < b ? a : b; }
__device__ __forceinline__ unsigned umx(unsigned a, unsigned b){ return a > b ? a : b; }

__device__ __forceinline__ void gload_lds16(const void* g, void* l) {
    __builtin_amdgcn_global_load_lds(
        (const __attribute__((address_space(1))) unsigned int*)g,
        (__attribute__((address_space(3))) unsigned int*)l, 16, 0, 0);
}

// ---------------------------------------------------------------------------
// csq (f64-exact -> f32) + w -> bf16 in swizzled k-blocked layout
// wbf[kt][code][64 k] bf16, 128B rows, byte ^= ((code&7)<<4)
__global__ __launch_bounds__(256)
void csq_wbf_kernel(const float* __restrict__ w, float* __restrict__ csq,
                    unsigned char* __restrict__ wbf)
{
    int j    = blockIdx.x * 4 + (threadIdx.x >> 6);
    int lane = threadIdx.x & 63;
    if (j >= NCODE) return;
    float4 v = *(const float4*)(w + (size_t)j * KDIM + lane * 4);
    double s = (double)v.x*v.x + (double)v.y*v.y + (double)v.z*v.z + (double)v.w*v.w;
    #pragma unroll
    for (int off = 1; off < 64; off <<= 1) s += __shfl_xor(s, off, 64);
    if (lane == 0) csq[j] = (float)s;

    int kt = lane >> 4;                    // k-block plane
    int o_lin = (lane & 15) * 8;           // byte within 128B row
    int o = o_lin ^ ((j & 7) << 4);
    uint2 pk;
    pk.x = (unsigned)f2bf(v.x) | ((unsigned)f2bf(v.y) << 16);
    pk.y = (unsigned)f2bf(v.z) | ((unsigned)f2bf(v.w) << 16);
    *(uint2*)(wbf + ((size_t)kt * NCODE + j) * 128 + o) = pk;
}

// ---------------------------------------------------------------------------
// x[b][k][p] f32 -> xbf[kt][row=b*1024+p][64 k] bf16, swizzled 128B rows
__global__ __launch_bounds__(256)
void prep_x_kernel(const float* __restrict__ x, unsigned char* __restrict__ xbf)
{
    __shared__ float Lt[64][65];
    int t  = threadIdx.x;
    int b  = blockIdx.x >> 6;
    int kt = (blockIdx.x >> 4) & 3;
    int pt = blockIdx.x & 15;

    #pragma unroll
    for (int rnd = 0; rnd < 16; ++rnd) {
        int kk = rnd * 4 + (t >> 6);
        int pp = t & 63;
        Lt[kk][pp] = x[((size_t)(b * 256 + kt * 64 + kk)) * 1024 + pt * 64 + pp];
    }
    __syncthreads();

    int p = t >> 2, q = t & 3;
    int row = b * 1024 + pt * 64 + p;
    int swz = (p & 7) << 4;
    #pragma unroll
    for (int s = 0; s < 2; ++s) {
        int kb = q * 16 + s * 8;
        unsigned w0 = (unsigned)f2bf(Lt[kb+0][p]) | ((unsigned)f2bf(Lt[kb+1][p]) << 16);
        unsigned w1 = (unsigned)f2bf(Lt[kb+2][p]) | ((unsigned)f2bf(Lt[kb+3][p]) << 16);
        unsigned w2 = (unsigned)f2bf(Lt[kb+4][p]) | ((unsigned)f2bf(Lt[kb+5][p]) << 16);
        unsigned w3 = (unsigned)f2bf(Lt[kb+6][p]) | ((unsigned)f2bf(Lt[kb+7][p]) << 16);
        int o = ((q * 32 + s * 16) ^ swz);
        uint4 pk; pk.x = w0; pk.y = w1; pk.z = w2; pk.w = w3;
        *(uint4*)(xbf + ((size_t)kt * ROWS + row) * 128 + o) = pk;
    }
}

// ---------------------------------------------------------------------------
// Stage 1: bf16 MFMA screening GEMM (dist key = csq - 2*dot), per-lane top-3
// packed keys; 16-lane butterfly -> per-wave (half-chunk) top-4; cross-wave
// LDS pair-merge -> per-chunk top-4 candidate columns.  NO races: each
// (row, chunk) part entry written by exactly one thread.
// Grid: 128 row-blocks x 4 chunks; block 256 thr; tile 128x128, BK=64.
__global__ __launch_bounds__(256, 2)
void stage1_kernel(const unsigned char* __restrict__ xbf,
                   const unsigned char* __restrict__ wbf,
                   const float* __restrict__ csq, uint4* __restrict__ part)
{
    __shared__ alignas(16) unsigned char As[16384];   // [128 rows][128B], swizzled
    __shared__ alignas(16) unsigned char Bs[16384];

    const int tid = threadIdx.x;
    const int wid = tid >> 6;
    const int l   = tid & 63;
    const int l15 = l & 15, g = l >> 4;
    const int rb    = blockIdx.x & 127;
    const int chunk = blockIdx.x >> 7;
    const int row0  = rb * 128;
    const int cbase = chunk * 2048;
    const int wr = wid >> 1, wc = wid & 1;

    unsigned key1[16], key2[16], key3[16];
    #pragma unroll
    for (int s = 0; s < 16; ++s) { key1[s]=0xFFFFFFFFu; key2[s]=0xFFFFFFFFu; key3[s]=0xFFFFFFFFu; }

    const int stoff = (wid * 4) * 1024;   // this wave's staging region base

    for (int t = 0; t < 16; ++t) {
        const int j0 = cbase + t * 128;
        f32x4 acc[4][4];
        #pragma unroll
        for (int mf = 0; mf < 4; ++mf)
            #pragma unroll
            for (int nf = 0; nf < 4; ++nf)
                acc[mf][nf] = (f32x4){0.f, 0.f, 0.f, 0.f};

        for (int kt = 0; kt < 4; ++kt) {
            size_t asrc = ((size_t)(kt * ROWS  + row0)) * 128;
            size_t bsrc = ((size_t)(kt * NCODE + j0  )) * 128;
            #pragma unroll
            for (int c = 0; c < 4; ++c) {
                int o = stoff + c * 1024;
                gload_lds16(xbf + asrc + o + l * 16, As + o);
                gload_lds16(wbf + bsrc + o + l * 16, Bs + o);
            }
            __syncthreads();
            #pragma unroll
            for (int ks = 0; ks < 2; ++ks) {
                bf16x8 af[4], bfr[4];
                #pragma unroll
                for (int mf = 0; mf < 4; ++mf) {
                    int row = wr * 64 + mf * 16 + l15;
                    int off = (ks * 64 + g * 16) ^ ((row & 7) << 4);
                    af[mf] = *(const bf16x8*)(As + row * 128 + off);
                }
                #pragma unroll
                for (int nf = 0; nf < 4; ++nf) {
                    int col = wc * 64 + nf * 16 + l15;
                    int off = (ks * 64 + g * 16) ^ ((col & 7) << 4);
                    bfr[nf] = *(const bf16x8*)(Bs + col * 128 + off);
                }
                #pragma unroll
                for (int mf = 0; mf < 4; ++mf)
                    #pragma unroll
                    for (int nf = 0; nf < 4; ++nf)
                        acc[mf][nf] = __builtin_amdgcn_mfma_f32_16x16x32_bf16(
                            af[mf], bfr[nf], acc[mf][nf], 0, 0, 0);
            }
            __syncthreads();
        }

        // fused screening epilogue: d = csq - 2*acc, pack key, top-3 update
        float cs[4];
        #pragma unroll
        for (int nf = 0; nf < 4; ++nf) cs[nf] = csq[j0 + wc * 64 + nf * 16 + l15];
        #pragma unroll
        for (int nf = 0; nf < 4; ++nf) {
            unsigned colid = (unsigned)(t * 128 + wc * 64 + nf * 16 + l15);
            #pragma unroll
            for (int mf = 0; mf < 4; ++mf) {
                #pragma unroll
                for (int r = 0; r < 4; ++r) {
                    float d = fmaf(-2.0f, acc[mf][nf][r], cs[nf]);
                    unsigned k = (mono(d) & 0xFFFFF800u) | colid;
                    const int s = mf * 4 + r;
                    unsigned t1 = umn(key1[s], k), t2 = umx(key1[s], k);
                    key1[s] = t1;
                    unsigned u1 = umn(key2[s], t2), u2 = umx(key2[s], t2);
                    key2[s] = u1;
                    key3[s] = umn(key3[s], u2);
                }
            }
        }
    }

    // butterfly merge over the 16-lane row-group -> per-wave sorted top-4
    // (top-4 of this wave's 64-column half-chunk slice), then stash keys in
    // LDS for the cross-wave (wc) pair-merge.
    uint4* red = (uint4*)As;              // dead after final barrier; 128*2*16B
    #pragma unroll
    for (int s = 0; s < 16; ++s) {
        unsigned v0 = key1[s], v1 = key2[s], v2 = key3[s], v3 = 0xFFFFFFFFu;
        #pragma unroll
        for (int off = 1; off < 16; off <<= 1) {
            unsigned o0 = __shfl_xor(v0, off, 64);
            unsigned o1 = __shfl_xor(v1, off, 64);
            unsigned o2 = __shfl_xor(v2, off, 64);
            unsigned o3 = __shfl_xor(v3, off, 64);
            unsigned w0 = umn(v0, o3), w1 = umn(v1, o2), w2 = umn(v2, o1), w3 = umn(v3, o0);
            unsigned a0 = umn(w0, w2), a2 = umx(w0, w2);
            unsigned a1 = umn(w1, w3), a3 = umx(w1, w3);
            v0 = umn(a0, a1); v1 = umx(a0, a1);
            v2 = umn(a2, a3); v3 = umx(a2, a3);
        }
        if (l15 == 0) {
            int mf = s >> 2, r = s & 3;
            int rloc = wr * 64 + mf * 16 + g * 4 + r;   // row within block
            uint4 o; o.x = v0; o.y = v1; o.z = v2; o.w = v3;
            red[rloc * 2 + wc] = o;
        }
    }
    __syncthreads();

    // cross-wave pair-merge: top-4 of two sorted-4 key lists, then emit codes
    if (tid < 128) {
        uint4 a = red[tid * 2 + 0];
        uint4 b = red[tid * 2 + 1];
        unsigned w0 = umn(a.x, b.w), w1 = umn(a.y, b.z);
        unsigned w2 = umn(a.z, b.y), w3 = umn(a.w, b.x);
        unsigned s0 = umn(w0, w2), s2 = umx(w0, w2);
        unsigned s1 = umn(w1, w3), s3 = umx(w1, w3);
        unsigned v0 = umn(s0, s1), v1 = umx(s0, s1);
        unsigned v2 = umn(s2, s3), v3 = umx(s2, s3);
        uint4 o;
        o.x = (unsigned)cbase + (v0 & 0x7FFu);
        o.y = (unsigned)cbase + (v1 & 0x7FFu);
        o.z = (unsigned)cbase + (v2 & 0x7FFu);
        o.w = (unsigned)cbase + (v3 & 0x7FFu);
        part[(size_t)(row0 + tid) * 4 + chunk] = o;
    }
}

// ---------------------------------------------------------------------------
// Refine: emulate reference f32 arithmetic for the 16 candidate columns.
//   d32 = fl32( fl32(S32 + csq32[j]) - fl32(2*dot_exact) ), numpy first-min.
__global__ __launch_bounds__(256)
void refine_kernel(const float* __restrict__ x, const float* __restrict__ w,
                   const float* __restrict__ csq, const unsigned* __restrict__ part,
                   int* __restrict__ codes, float* __restrict__ code_out)
{
    int row  = blockIdx.x * 4 + (threadIdx.x >> 6);
    int lane = threadIdx.x & 63;
    if (row >= ROWS) return;
    int b = row >> 10, p = row & 1023;
    const float* xb = x + (size_t)b * (C_ * HW) + p;

    float xs[4];
    #pragma unroll
    for (int m = 0; m < 4; ++m) xs[m] = xb[(size_t)(lane * 4 + m) * HW];

    double ss = (double)xs[0]*xs[0] + (double)xs[1]*xs[1]
              + (double)xs[2]*xs[2] + (double)xs[3]*xs[3];
    #pragma unroll
    for (int off = 1; off < 64; off <<= 1) ss += __shfl_xor(ss, off, 64);
    float S32 = (float)ss;

    float bestd = FLT_MAX; int besti = INT_MAX;
    #pragma unroll 4
    for (int c = 0; c < 16; ++c) {
        int ci = (int)part[(size_t)row * 16 + c];
        float4 wv = *(const float4*)(w + (size_t)ci * KDIM + lane * 4);
        double acc = (double)wv.x*xs[0] + (double)wv.y*xs[1]
                   + (double)wv.z*xs[2] + (double)wv.w*xs[3];
        #pragma unroll
        for (int off = 1; off < 64; off <<= 1) acc += __shfl_xor(acc, off, 64);
        float tt = (float)(2.0 * acc);
        float sc = S32 + csq[ci];
        float d  = sc - tt;
        if (d < bestd || (d == bestd && ci < besti)) { bestd = d; besti = ci; }
    }

    if (lane == 0) {
        codes[row]    = besti;
        code_out[row] = (float)besti;
    }
}

// ---------------------------------------------------------------------------
__global__ __launch_bounds__(256)
void output_kernel(const float* __restrict__ x, const float* __restrict__ w,
                   const int* __restrict__ codes, float* __restrict__ xq,
                   double* __restrict__ partials)
{
    int bid = blockIdx.x;
    int pc  = bid & 3;
    int c   = (bid >> 2) & 255;
    int b   = bid >> 10;
    int p   = pc * 256 + threadIdx.x;
    int r   = b * 1024 + p;
    int code = codes[r];
    size_t o = (size_t)b * (256 * HW) + (size_t)c * HW + p;
    float val  = w[(size_t)code * KDIM + c];
    xq[o] = val;
    float diff = val - x[o];
    double sq = (double)diff * (double)diff;

    __shared__ double sred[256];
    sred[threadIdx.x] = sq;
    __syncthreads();
    for (int s = 128; s > 0; s >>= 1) {
        if (threadIdx.x < s) sred[threadIdx.x] += sred[threadIdx.x + s];
        __syncthreads();
    }
    if (threadIdx.x == 0) partials[bid] = sred[0];
}

__global__ __launch_bounds__(256)
void loss_kernel(const double* __restrict__ partials, float* __restrict__ loss_out)
{
    __shared__ double sred[256];
    double s = 0.0;
    for (int i = threadIdx.x; i < 16384; i += 256) s += partials[i];
    sred[threadIdx.x] = s;
    __syncthreads();
    for (int k = 128; k > 0; k >>= 1) {
        if (threadIdx.x < k) sred[threadIdx.x] += sred[threadIdx.x + k];
        __syncthreads();
    }
    if (threadIdx.x == 0)
        loss_out[0] = (float)(sred[0] * (1.25 / (double)(B_ * 256 * HW)));
}

// ---------------------------------------------------------------------------
extern "C" void kernel_launch(void* const* d_in, const int* in_sizes, int n_in,
                              void* d_out, int out_size, void* d_ws, size_t ws_size,
                              hipStream_t stream)
{
    const float* x = (const float*)d_in[0];   // (16,256,32,32)
    const float* w = (const float*)d_in[1];   // (8193,256)
    float* out    = (float*)d_out;
    float* xq     = out;
    float* loss   = out + 4194304;
    float* code_f = out + 4194305;

    char* ws = (char*)d_ws;
    float*         csq      = (float*)(ws);                      // 32 KB
    int*           codes    = (int*)(ws + 32*1024);              // 64 KB
    double*        partials = (double*)(ws + 128*1024);          // 128 KB
    uint4*         part     = (uint4*)(ws + 256*1024);           // 1 MB
    unsigned char* xbf      = (unsigned char*)(ws + 2*1024*1024);  // 8 MB
    unsigned char* wbf      = (unsigned char*)(ws + 10*1024*1024); // 4 MB

    csq_wbf_kernel<<<NCODE/4, 256, 0, stream>>>(w, csq, wbf);
    prep_x_kernel <<<1024,    256, 0, stream>>>(x, xbf);
    stage1_kernel <<<512,     256, 0, stream>>>(xbf, wbf, csq, part);
    refine_kernel <<<ROWS/4,  256, 0, stream>>>(x, w, csq, (const unsigned*)part, codes, code_f);
    output_kernel <<<16384,   256, 0, stream>>>(x, w, codes, xq, partials);
    loss_kernel   <<<1,       256, 0, stream>>>(partials, loss);
}